// Round 8
// baseline (367.605 us; speedup 1.0000x reference)
//
#include <hip/hip_runtime.h>
#include <hip/hip_bf16.h>

// Problem constants (match reference)
constexpr int cB  = 8;
constexpr int cS  = 4096;
constexpr int cH  = 768;
constexpr int cNH = 12;
constexpr int cL  = 2;
constexpr int cNS = 64;
constexpr int cDH = 64;
constexpr int cM  = cB * cNS;  // 512 rows of activations

typedef __attribute__((ext_vector_type(8))) short bf16x8;
typedef __attribute__((ext_vector_type(4))) float f32x4;
typedef __attribute__((ext_vector_type(4))) unsigned short u16x4;

__device__ __forceinline__ float b2f(unsigned short u) {
    union { float f; unsigned int i; } x; x.i = (unsigned int)u << 16; return x.f;
}
__device__ __forceinline__ unsigned short f2b(float f) {
    __hip_bfloat16 h = __float2bfloat16(f);
    return *(unsigned short*)&h;
}

// ---------------------------------------------------------------------------
// 1) Fused prep, 768 threads/block (verified R7):
//    blocks [0,512): segment-mean pooling, four 192-thread row-groups;
//    blocks [512,896): weight transpose+convert, 3 tiles/block.
// ---------------------------------------------------------------------------
union PrepShared {
    struct { int cnt; int list[cS]; float ps[3][192][4]; } p;  // 25.6 KB
    float T[3][64][65];                                        // 49.9 KB
};

__global__ __launch_bounds__(768) void prep_kernel(
    const int* __restrict__ sent_ind, const float* __restrict__ sl,
    __hip_bfloat16* __restrict__ xb,
    const float* __restrict__ Wq, const float* __restrict__ Wk,
    const float* __restrict__ Wv, const float* __restrict__ Wo,
    __hip_bfloat16* __restrict__ wt)
{
    __shared__ PrepShared sh;
    int tid = threadIdx.x;

    if (blockIdx.x < (unsigned)cM) {
        // ---------------- pool ----------------
        int bn = blockIdx.x;
        int b = bn >> 6, n = bn & (cNS - 1);
        if (tid == 0) sh.p.cnt = 0;
        __syncthreads();
        const int* si = sent_ind + (size_t)b * cS;
        for (int s = tid; s < cS; s += 768)
            if (s != 0 && si[s] == n) { int p = atomicAdd(&sh.p.cnt, 1); sh.p.list[p] = s; }
        __syncthreads();
        int c = sh.p.cnt;
        int grp = tid / 192;         // 0..3 row-groups
        int t   = tid % 192;
        int qtr = c >> 2;
        int lo = grp * qtr;
        int hi = (grp == 3) ? c : lo + qtr;
        const float* bbase = sl + (size_t)b * cS * cH;
        int col = t * 4;
        float4 a0 = {0.f, 0.f, 0.f, 0.f};
        float4 a1 = {0.f, 0.f, 0.f, 0.f};
        float4 a2 = {0.f, 0.f, 0.f, 0.f};
        float4 a3 = {0.f, 0.f, 0.f, 0.f};
        int i = lo;
        for (; i + 4 <= hi; i += 4) {
            float4 r0 = *(const float4*)(bbase + (size_t)sh.p.list[i + 0] * cH + col);
            float4 r1 = *(const float4*)(bbase + (size_t)sh.p.list[i + 1] * cH + col);
            float4 r2 = *(const float4*)(bbase + (size_t)sh.p.list[i + 2] * cH + col);
            float4 r3 = *(const float4*)(bbase + (size_t)sh.p.list[i + 3] * cH + col);
            a0.x += r0.x; a0.y += r0.y; a0.z += r0.z; a0.w += r0.w;
            a1.x += r1.x; a1.y += r1.y; a1.z += r1.z; a1.w += r1.w;
            a2.x += r2.x; a2.y += r2.y; a2.z += r2.z; a2.w += r2.w;
            a3.x += r3.x; a3.y += r3.y; a3.z += r3.z; a3.w += r3.w;
        }
        for (; i < hi; ++i) {
            float4 r0 = *(const float4*)(bbase + (size_t)sh.p.list[i] * cH + col);
            a0.x += r0.x; a0.y += r0.y; a0.z += r0.z; a0.w += r0.w;
        }
        float s0 = a0.x + a1.x + a2.x + a3.x;
        float s1 = a0.y + a1.y + a2.y + a3.y;
        float s2 = a0.z + a1.z + a2.z + a3.z;
        float s3 = a0.w + a1.w + a2.w + a3.w;
        if (grp) {
            sh.p.ps[grp - 1][t][0] = s0; sh.p.ps[grp - 1][t][1] = s1;
            sh.p.ps[grp - 1][t][2] = s2; sh.p.ps[grp - 1][t][3] = s3;
        }
        __syncthreads();
        if (grp == 0) {
            float inv = 1.0f / (float)c;
            s0 += sh.p.ps[0][t][0] + sh.p.ps[1][t][0] + sh.p.ps[2][t][0];
            s1 += sh.p.ps[0][t][1] + sh.p.ps[1][t][1] + sh.p.ps[2][t][1];
            s2 += sh.p.ps[0][t][2] + sh.p.ps[1][t][2] + sh.p.ps[2][t][2];
            s3 += sh.p.ps[0][t][3] + sh.p.ps[1][t][3] + sh.p.ps[2][t][3];
            __hip_bfloat16* xr = xb + (size_t)bn * cH + col;
            xr[0] = __float2bfloat16(s0 * inv);
            xr[1] = __float2bfloat16(s1 * inv);
            xr[2] = __float2bfloat16(s2 * inv);
            xr[3] = __float2bfloat16(s3 * inv);
        }
    } else {
        // ---------------- wconv: 3 tiles per block ----------------
        int sub = tid >> 8;                         // 0..2
        int t   = tid & 255;
        int bi = (blockIdx.x - cM) * 3 + sub;       // 0..1151 = (12 x 12 x 8)
        int bx = bi % 12, by = (bi / 12) % 12, mat = bi / 144;
        int layer = mat >> 2, which = mat & 3;
        const float* W = (which == 0 ? Wq : which == 1 ? Wk : which == 2 ? Wv : Wo)
                         + (size_t)layer * cH * cH;
        int k0 = by * 64, n0 = bx * 64;
        int r = t >> 2, cb = (t & 3) * 16;
        #pragma unroll
        for (int u = 0; u < 4; ++u) {
            float4 w4 = *(const float4*)(W + (size_t)(k0 + r) * cH + n0 + cb + u * 4);
            sh.T[sub][r][cb + u * 4 + 0] = w4.x; sh.T[sub][r][cb + u * 4 + 1] = w4.y;
            sh.T[sub][r][cb + u * 4 + 2] = w4.z; sh.T[sub][r][cb + u * 4 + 3] = w4.w;
        }
        __syncthreads();
        int nn = t >> 2, kseg = (t & 3) * 16;
        __hip_bfloat16 tmp[16] __attribute__((aligned(16)));
        #pragma unroll
        for (int j = 0; j < 16; ++j)
            tmp[j] = __float2bfloat16(sh.T[sub][kseg + j][nn]);
        __hip_bfloat16* dst = wt + ((size_t)mat * cH + n0 + nn) * cH + k0 + kseg;
        *(bf16x8*)(dst)     = *(const bf16x8*)(tmp);
        *(bf16x8*)(dst + 8) = *(const bf16x8*)(tmp + 8);
    }
}

// ---------------------------------------------------------------------------
// 2) Fused qkv + attention v2: 96 blocks x 1024 threads (16 waves = 4/SIMD
//    on the active CUs -- the old fused kernel's 1 wave/SIMD was the 31us
//    diagnosis, r6). GEMM: 48 output tiles (3 mats x 16); wave w has
//    rowt=w&3 (A-frag shared across its 3 combos), combos idx=(w>>2)*3+j ->
//    mat=idx>>2, colt=idx&3. 1 A-load + 3 B-loads per k-step per wave.
//    Then all-MFMA attention via LDS-staged Q/K/V^T (r7-verified mapping).
// ---------------------------------------------------------------------------
struct QAShared {
    unsigned short Qs[cNS][72];   // 9.2 KB  (q, scaled+bias, bf16)
    unsigned short Ks[cNS][72];   // 9.2 KB
    unsigned short Vt[cDH][72];   // 9.2 KB  (V^T: [d][s])
    unsigned short P [cNS][72];   // 9.2 KB  (probs bf16)
    float S[cNS][68];             // 17.4 KB (scores f32)
};

__global__ __launch_bounds__(1024) void qkvattn2_kernel(
    const __hip_bfloat16* __restrict__ x_bf,
    const __hip_bfloat16* __restrict__ wqkv,   // [3][H][H] n-major
    const float* __restrict__ bq, const float* __restrict__ bk,
    const float* __restrict__ bv,
    __hip_bfloat16* __restrict__ ctx_bf)
{
    __shared__ QAShared sh;
    int tid = threadIdx.x;
    int lane = tid & 63, wave = tid >> 6;
    int l15 = lane & 15, q4 = lane >> 4;
    int b = blockIdx.x / cNH, h = blockIdx.x % cNH;

    // ---- QKV GEMM: wave -> rowt = wave&3, combos (mat,colt) ----
    int rowt = wave & 3;
    int widx = wave >> 2;            // 0..3
    int mats[3], colts[3];
    const __hip_bfloat16* Brow[3];
    #pragma unroll
    for (int j = 0; j < 3; ++j) {
        int idx = widx * 3 + j;      // 0..11
        mats[j] = idx >> 2; colts[j] = idx & 3;
        Brow[j] = wqkv + (size_t)mats[j] * cH * cH
                + (size_t)(h * 64 + colts[j] * 16 + l15) * cH + q4 * 8;
    }
    const __hip_bfloat16* Arow =
        x_bf + (size_t)(b * 64 + rowt * 16 + l15) * cH + q4 * 8;

    f32x4 acc[3];
    #pragma unroll
    for (int j = 0; j < 3; ++j) acc[j] = (f32x4){0.f, 0.f, 0.f, 0.f};

    bf16x8 a, bw[3], an, bn[3];
    a = *(const bf16x8*)(Arow);
    #pragma unroll
    for (int j = 0; j < 3; ++j) bw[j] = *(const bf16x8*)(Brow[j]);
    #pragma unroll 4
    for (int k0 = 0; k0 < cH; k0 += 32) {
        if (k0 + 32 < cH) {
            an = *(const bf16x8*)(Arow + k0 + 32);
            #pragma unroll
            for (int j = 0; j < 3; ++j) bn[j] = *(const bf16x8*)(Brow[j] + k0 + 32);
        }
        #pragma unroll
        for (int j = 0; j < 3; ++j)
            acc[j] = __builtin_amdgcn_mfma_f32_16x16x32_bf16(a, bw[j], acc[j], 0, 0, 0);
        a = an;
        #pragma unroll
        for (int j = 0; j < 3; ++j) bw[j] = bn[j];
    }

    // bias (+0.125 scale for q) -> LDS staging
    #pragma unroll
    for (int j = 0; j < 3; ++j) {
        int mat = mats[j], colt = colts[j];
        int col_d = colt * 16 + l15;
        float bias = (mat == 0 ? bq : mat == 1 ? bk : bv)[h * 64 + col_d];
        #pragma unroll
        for (int r = 0; r < 4; ++r) {
            int row_s = rowt * 16 + q4 * 4 + r;   // sequence index
            float v = acc[j][r] + bias;
            if (mat == 0)      sh.Qs[row_s][col_d] = f2b(v * 0.125f);
            else if (mat == 1) sh.Ks[row_s][col_d] = f2b(v);
            else               sh.Vt[col_d][row_s] = f2b(v);
        }
    }
    __syncthreads();

    // ---- QK^T: wave -> S tile (rowt2 = wave>>2, colt2 = wave&3) ----
    {
        int rt = wave >> 2, ct = wave & 3;
        bf16x8 aq0 = *(const bf16x8*)&sh.Qs[rt * 16 + l15][q4 * 8];
        bf16x8 aq1 = *(const bf16x8*)&sh.Qs[rt * 16 + l15][32 + q4 * 8];
        bf16x8 bk0 = *(const bf16x8*)&sh.Ks[ct * 16 + l15][q4 * 8];
        bf16x8 bk1 = *(const bf16x8*)&sh.Ks[ct * 16 + l15][32 + q4 * 8];
        f32x4 sc = (f32x4){0.f, 0.f, 0.f, 0.f};
        sc = __builtin_amdgcn_mfma_f32_16x16x32_bf16(aq0, bk0, sc, 0, 0, 0);
        sc = __builtin_amdgcn_mfma_f32_16x16x32_bf16(aq1, bk1, sc, 0, 0, 0);
        #pragma unroll
        for (int r = 0; r < 4; ++r)
            sh.S[rt * 16 + q4 * 4 + r][ct * 16 + l15] = sc[r];
    }
    __syncthreads();

    // ---- softmax: 64 rows x 16 threads, 4 cols/thread ----
    {
        int row = tid >> 4, jq = tid & 15;
        float e[4];
        float m = -1e30f;
        #pragma unroll
        for (int c = 0; c < 4; ++c) { e[c] = sh.S[row][jq * 4 + c]; m = fmaxf(m, e[c]); }
        m = fmaxf(m, __shfl_xor(m, 1));
        m = fmaxf(m, __shfl_xor(m, 2));
        m = fmaxf(m, __shfl_xor(m, 4));
        m = fmaxf(m, __shfl_xor(m, 8));
        float s = 0.f;
        #pragma unroll
        for (int c = 0; c < 4; ++c) { e[c] = __expf(e[c] - m); s += e[c]; }
        s += __shfl_xor(s, 1);
        s += __shfl_xor(s, 2);
        s += __shfl_xor(s, 4);
        s += __shfl_xor(s, 8);
        float inv = 1.0f / s;
        #pragma unroll
        for (int c = 0; c < 4; ++c) sh.P[row][jq * 4 + c] = f2b(e[c] * inv);
    }
    __syncthreads();

    // ---- PV: wave -> O tile (rt, dt=ct). O[q][d] = sum_s P[q][s]*Vt[d][s] --
    {
        int rt = wave >> 2, ct = wave & 3;
        bf16x8 ap0 = *(const bf16x8*)&sh.P[rt * 16 + l15][q4 * 8];
        bf16x8 ap1 = *(const bf16x8*)&sh.P[rt * 16 + l15][32 + q4 * 8];
        bf16x8 bv0 = *(const bf16x8*)&sh.Vt[ct * 16 + l15][q4 * 8];
        bf16x8 bv1 = *(const bf16x8*)&sh.Vt[ct * 16 + l15][32 + q4 * 8];
        f32x4 o = (f32x4){0.f, 0.f, 0.f, 0.f};
        o = __builtin_amdgcn_mfma_f32_16x16x32_bf16(ap0, bv0, o, 0, 0, 0);
        o = __builtin_amdgcn_mfma_f32_16x16x32_bf16(ap1, bv1, o, 0, 0, 0);
        #pragma unroll
        for (int r = 0; r < 4; ++r) {
            int q = rt * 16 + q4 * 4 + r;
            ctx_bf[(size_t)(b * cNS + q) * cH + h * cDH + ct * 16 + l15] =
                __float2bfloat16(o[r]);
        }
    }
}

// ---------------------------------------------------------------------------
// 3) O-GEMM + bias + GELU + in-block LayerNorm (verified R5 kernel).
//    Grid 32 x 512: block owns 16 complete rows; wave w -> n-slice w*96
//    (6 MFMA tiles: acc 24 + frag ~56 VGPR, no register starvation).
//    LN block-local (no fence); h stays in LDS.
// ---------------------------------------------------------------------------
__global__ __launch_bounds__(512, 1) void ogemm_ln_kernel(
    const __hip_bfloat16* __restrict__ A,      // ctx_bf [M][H]
    const __hip_bfloat16* __restrict__ Wt,     // [H][H] n-major
    const float* __restrict__ bias,
    const float* __restrict__ g, const float* __restrict__ bb,
    __hip_bfloat16* __restrict__ xb,           // LN out bf16 [M][H]
    float* __restrict__ outf)                  // LN out f32 (last layer) or null
{
    __shared__ unsigned short hs[16][776];     // h tile (bf16 bits), 24.3 KB
    int tid  = threadIdx.x;
    int lane = tid & 63;
    int wave = tid >> 6;
    int l15 = lane & 15, q4 = lane >> 4;
    int r0 = blockIdx.x * 16;
    int nb = wave * 96;                        // 6 n-tiles of 16

    const __hip_bfloat16* Arow = A  + (size_t)(r0 + l15) * cH + q4 * 8;
    const __hip_bfloat16* Wr   = Wt + (size_t)(nb + l15) * cH + q4 * 8;

    f32x4 acc[6];
    #pragma unroll
    for (int j = 0; j < 6; ++j) acc[j] = (f32x4){0.f, 0.f, 0.f, 0.f};

    bf16x8 a, bw[6], an, bn[6];
    a = *(const bf16x8*)(Arow);
    #pragma unroll
    for (int j = 0; j < 6; ++j) bw[j] = *(const bf16x8*)(Wr + (size_t)j * 16 * cH);
    #pragma unroll
    for (int k0 = 0; k0 < cH; k0 += 32) {
        if (k0 + 32 < cH) {
            an = *(const bf16x8*)(Arow + k0 + 32);
            #pragma unroll
            for (int j = 0; j < 6; ++j)
                bn[j] = *(const bf16x8*)(Wr + (size_t)j * 16 * cH + k0 + 32);
        }
        #pragma unroll
        for (int j = 0; j < 6; ++j)
            acc[j] = __builtin_amdgcn_mfma_f32_16x16x32_bf16(a, bw[j], acc[j], 0, 0, 0);
        a = an;
        #pragma unroll
        for (int j = 0; j < 6; ++j) bw[j] = bn[j];
    }

    // bias + GELU -> LDS (bf16 bits, matching baseline's bf16 h numerics)
    #pragma unroll
    for (int j = 0; j < 6; ++j) {
        int col = nb + j * 16 + l15;
        float bv = bias[col];
        #pragma unroll
        for (int r = 0; r < 4; ++r) {
            float v = acc[j][r] + bv;
            v = 0.5f * v * (1.0f + erff(v * 0.70710678118654752f));
            hs[q4 * 4 + r][col] = f2b(v);
        }
    }
    __syncthreads();

    // ---- in-block LN: wave handles rows wave*2, wave*2+1; 12 elems/lane ---
    float gv[12], bv2[12];
    {
        const float* gp = g  + lane * 12;
        const float* bp = bb + lane * 12;
        #pragma unroll
        for (int j = 0; j < 3; ++j) {
            float4 g4 = *(const float4*)(gp + j * 4);
            float4 b4 = *(const float4*)(bp + j * 4);
            gv[j * 4 + 0] = g4.x; gv[j * 4 + 1] = g4.y;
            gv[j * 4 + 2] = g4.z; gv[j * 4 + 3] = g4.w;
            bv2[j * 4 + 0] = b4.x; bv2[j * 4 + 1] = b4.y;
            bv2[j * 4 + 2] = b4.z; bv2[j * 4 + 3] = b4.w;
        }
    }
    #pragma unroll
    for (int rr = 0; rr < 2; ++rr) {
        int lrow = wave * 2 + rr;
        int grow = r0 + lrow;
        const unsigned short* hr = &hs[lrow][lane * 12];
        float v[12];
        #pragma unroll
        for (int j = 0; j < 3; ++j) {
            u16x4 q = *(const u16x4*)(hr + j * 4);
            v[j * 4 + 0] = b2f(q[0]); v[j * 4 + 1] = b2f(q[1]);
            v[j * 4 + 2] = b2f(q[2]); v[j * 4 + 3] = b2f(q[3]);
        }
        float s = 0.f;
        #pragma unroll
        for (int j = 0; j < 12; ++j) s += v[j];
        #pragma unroll
        for (int o = 32; o; o >>= 1) s += __shfl_xor(s, o);
        float mu = s * (1.0f / 768.0f);
        float ss = 0.f;
        #pragma unroll
        for (int j = 0; j < 12; ++j) { v[j] -= mu; ss += v[j] * v[j]; }
        #pragma unroll
        for (int o = 32; o; o >>= 1) ss += __shfl_xor(ss, o);
        float var = ss * (1.0f / 768.0f);
        float inv = rsqrtf(var + 1e-12f);
        float o12[12];
        #pragma unroll
        for (int j = 0; j < 12; ++j) o12[j] = v[j] * inv * gv[j] + bv2[j];

        unsigned short* xr = (unsigned short*)(xb + (size_t)grow * cH) + lane * 12;
        #pragma unroll
        for (int j = 0; j < 3; ++j) {
            u16x4 q;
            q[0] = f2b(o12[j * 4 + 0]); q[1] = f2b(o12[j * 4 + 1]);
            q[2] = f2b(o12[j * 4 + 2]); q[3] = f2b(o12[j * 4 + 3]);
            *(u16x4*)(xr + j * 4) = q;
        }
        if (outf) {
            float* orow = outf + (size_t)grow * cH + lane * 12;
            #pragma unroll
            for (int j = 0; j < 3; ++j) {
                float4 o4 = { o12[j * 4 + 0], o12[j * 4 + 1],
                              o12[j * 4 + 2], o12[j * 4 + 3] };
                *(float4*)(orow + j * 4) = o4;
            }
        }
    }
}

// ---------------------------------------------------------------------------
extern "C" void kernel_launch(void* const* d_in, const int* in_sizes, int n_in,
                              void* d_out, int out_size, void* d_ws, size_t ws_size,
                              hipStream_t stream) {
    const int*   sent_ind = (const int*)d_in[0];
    const float* start    = (const float*)d_in[1];
    const float* Wq = (const float*)d_in[2];
    const float* bq = (const float*)d_in[3];
    const float* Wk = (const float*)d_in[4];
    const float* bk = (const float*)d_in[5];
    const float* Wv = (const float*)d_in[6];
    const float* bv = (const float*)d_in[7];
    const float* Wo = (const float*)d_in[8];
    const float* bo = (const float*)d_in[9];
    const float* ln_g = (const float*)d_in[10];
    const float* ln_b = (const float*)d_in[11];
    float* out = (float*)d_out;

    char* w = (char*)d_ws;
    const size_t MH = 786432;  // M*H bf16 bytes
    __hip_bfloat16* wt     = (__hip_bfloat16*)w;                   // 8*H*H bf16
    __hip_bfloat16* x_bf   = (__hip_bfloat16*)(w + 9437184);
    __hip_bfloat16* ctx_bf = (__hip_bfloat16*)(w + 9437184 + MH);

    prep_kernel<<<cM + 384, 768, 0, stream>>>(sent_ind, start, x_bf,
                                              Wq, Wk, Wv, Wo, wt);

    for (int i = 0; i < cL; ++i) {
        const __hip_bfloat16* wqkv = wt + (size_t)(i * 4) * cH * cH;
        const __hip_bfloat16* wto  = wt + (size_t)(i * 4 + 3) * cH * cH;
        qkvattn2_kernel<<<cB * cNH, 1024, 0, stream>>>(
            x_bf, wqkv, bq + (size_t)i * cH, bk + (size_t)i * cH, bv + (size_t)i * cH,
            ctx_bf);
        ogemm_ln_kernel<<<32, 512, 0, stream>>>(
            ctx_bf, wto, bo + (size_t)i * cH,
            ln_g + (size_t)i * cH, ln_b + (size_t)i * cH,
            x_bf, (i == cL - 1) ? out : nullptr);
    }
}